// Round 7
// baseline (14853.004 us; speedup 1.0000x reference)
//
#include <hip/hip_runtime.h>
#include <stdint.h>

// BiLSTM (3-layer, bidirectional, 3-gate custom cell, highway) for MI355X.
//
// R7: controlled bisect from the R5 PASS (11.95 ms, absmax 4.7e-3).
// R6's scan-order-Z rewrite failed (absmax 0.35) and resisted inspection;
// reverted. This round keeps R5's EXACT dataflow (row-major fp16 Z, same
// pregemm/highway/transpose code) and applies only the three scan latency
// fixes, each semantically inert:
//  1. amdgpu_waves_per_eu(2,2): 256-VGPR budget -> wB (192 VGPRs of W_h
//     fragments) stays register-resident instead of scratch-spilled
//     (R5: VGPR_Count=128 => reload-per-step => 3.71 us/step).
//  2. Z prefetch one step ahead into u16 regs (24 scattered loads; single
//     per-lane base + immediate offsets; vmcnt wait lands a full step later).
//  3. Double-buffered h_lds: one barrier per step.
// Scan remains 4 independent blocks (dir x batch-half), block=512, no
// inter-block sync. Outputs fp32. ws ~182.5 MiB.

typedef unsigned short u16;
typedef unsigned int u32;
typedef unsigned long long u64;
typedef __attribute__((ext_vector_type(8))) short short8;   // 8 bf16
typedef __attribute__((ext_vector_type(4))) float f32x4;

#define MFMA16(a, b, c) __builtin_amdgcn_mfma_f32_16x16x32_bf16((a), (b), (c), 0, 0, 0)

__device__ __forceinline__ float b2f(u16 u) {
  u32 v = ((u32)u) << 16;
  return __builtin_bit_cast(float, v);
}
__device__ __forceinline__ u16 f2b(float f) {  // round-to-nearest-even
  u32 u = __builtin_bit_cast(u32, f);
  u32 r = u + 0x7FFFu + ((u >> 16) & 1u);
  return (u16)(r >> 16);
}
__device__ __forceinline__ u16 f2h(float f) {  // fp32 -> fp16 bits
  return __builtin_bit_cast(u16, (_Float16)f);
}
__device__ __forceinline__ float h2f(u16 u) {  // fp16 bits -> fp32
  return (float)__builtin_bit_cast(_Float16, u);
}
// Overflow-proof activations: exp args always <= 0 -> no inf/NaN possible.
__device__ __forceinline__ float sigm(float x) {
  const float q = __expf(-fabsf(x));
  const float r = 1.f / (1.f + q);
  return x >= 0.f ? r : 1.f - r;
}
__device__ __forceinline__ float tanh_f(float x) {
  const float q = __expf(-2.f * fabsf(x));
  const float t = (1.f - q) / (1.f + q);
  return x >= 0.f ? t : -t;
}

// ---------------------------------------------------------------------------
// Convert x (fp32) -> bf16, vectorized float4.
// ---------------------------------------------------------------------------
__global__ void k_convert(const float* __restrict__ src, u16* __restrict__ dst, int n4) {
  int i = blockIdx.x * 256 + threadIdx.x;
  if (i < n4) {
    float4 v = ((const float4*)src)[i];
    ushort4 o;
    o.x = f2b(v.x); o.y = f2b(v.y); o.z = f2b(v.z); o.w = f2b(v.w);
    ((ushort4*)dst)[i] = o;
  }
}

// ---------------------------------------------------------------------------
// Transpose + convert all weight matrices (fp32 W[R][C] -> bf16 Wt[C][R]).
// ---------------------------------------------------------------------------
__global__ void k_transpose(const float* __restrict__ w0, const float* __restrict__ w1,
                            const float* __restrict__ w2, const float* __restrict__ w3,
                            const float* __restrict__ w4, const float* __restrict__ w5,
                            const float* __restrict__ w6, u16* __restrict__ wt) {
  int z = blockIdx.y;
  const float* src;
  int R, C;
  size_t off;
  switch (z) {
    case 0: src = w0; R = 512; C = 768; off = 0u; break;
    case 1: src = w1; R = 512; C = 768; off = 393216u; break;
    case 2: src = w2; R = 768; C = 768; off = 786432u; break;
    case 3: src = w3; R = 768; C = 768; off = 1376256u; break;
    case 4: src = w4; R = 768; C = 768; off = 1966080u; break;
    case 5: src = w5; R = 768; C = 768; off = 2555904u; break;
    default: src = w6; R = 512; C = 512; off = 3145728u; break;
  }
  size_t total = (size_t)R * C;
  size_t e = (size_t)blockIdx.x * 256 + threadIdx.x;
  if (e < total) {
    int cc = (int)(e / (size_t)R);
    int rr = (int)(e - (size_t)cc * R);
    wt[off + e] = f2b(src[(size_t)rr * C + cc]);
  }
}

// ---------------------------------------------------------------------------
// Pre-GEMM: Z[m][n] = fp16( sum_k A[m][k]*Wt[n][k] + bias[n] )  (row-major)
// A bf16 [32768][Ka]; grid=(256, 6, 2[dir]); block=256; 128x128 tile.
// EXACT R5 code (passing).
// ---------------------------------------------------------------------------
__launch_bounds__(256) __global__
void k_pregemm(const u16* __restrict__ A, int Ka,
               const u16* __restrict__ WtF, const u16* __restrict__ WtB, int Kb,
               const float* __restrict__ biasF, const float* __restrict__ biasB,
               u16* __restrict__ ZF, u16* __restrict__ ZB) {
  const int dir = blockIdx.z;
  const u16* Bt = dir ? WtB : WtF;
  const float* bias = dir ? biasB : biasF;
  u16* Z = dir ? ZB : ZF;
  const int m0 = blockIdx.x * 128;
  const int n0 = blockIdx.y * 128;

  __shared__ u16 lA[128 * 40];
  __shared__ u16 lB[128 * 40];

  const int tid = threadIdx.x;
  const int wave = tid >> 6, lane = tid & 63, quad = lane >> 4, l15 = lane & 15;
  const int wy = wave >> 1, wx = wave & 1;
  const int r = tid >> 2, kc = tid & 3;

  f32x4 acc[4][4];
#pragma unroll
  for (int i = 0; i < 4; ++i)
#pragma unroll
    for (int j = 0; j < 4; ++j)
#pragma unroll
      for (int k = 0; k < 4; ++k) acc[i][j][k] = 0.f;

  const int nk = Ka >> 5;
  for (int kk = 0; kk < nk; ++kk) {
    const u16* Ap = A + (size_t)(m0 + r) * Ka + kk * 32 + kc * 8;
    uint4 a0 = *(const uint4*)Ap;
    uint4 a1 = *(const uint4*)(Ap + (size_t)64 * Ka);
    const u16* Bp = Bt + (size_t)(n0 + r) * Kb + kk * 32 + kc * 8;
    uint4 b0 = *(const uint4*)Bp;
    uint4 b1 = *(const uint4*)(Bp + (size_t)64 * Kb);
    __syncthreads();
    *(uint4*)&lA[r * 40 + kc * 8] = a0;
    *(uint4*)&lA[(r + 64) * 40 + kc * 8] = a1;
    *(uint4*)&lB[r * 40 + kc * 8] = b0;
    *(uint4*)&lB[(r + 64) * 40 + kc * 8] = b1;
    __syncthreads();
    short8 af[4], bf[4];
#pragma unroll
    for (int mt = 0; mt < 4; ++mt)
      af[mt] = *(const short8*)&lA[(wy * 64 + mt * 16 + l15) * 40 + quad * 8];
#pragma unroll
    for (int nt = 0; nt < 4; ++nt)
      bf[nt] = *(const short8*)&lB[(wx * 64 + nt * 16 + l15) * 40 + quad * 8];
#pragma unroll
    for (int mt = 0; mt < 4; ++mt)
#pragma unroll
      for (int nt = 0; nt < 4; ++nt) acc[mt][nt] = MFMA16(af[mt], bf[nt], acc[mt][nt]);
  }

#pragma unroll
  for (int nt = 0; nt < 4; ++nt) {
    const int col = n0 + wx * 64 + nt * 16 + l15;
    const float bv = bias[col];
#pragma unroll
    for (int mt = 0; mt < 4; ++mt) {
      const int mbase = m0 + wy * 64 + mt * 16 + quad * 4;
#pragma unroll
      for (int rr = 0; rr < 4; ++rr)
        Z[(size_t)(mbase + rr) * 768 + col] = f2h(acc[mt][nt][rr] + bv);
    }
  }
}

// ---------------------------------------------------------------------------
// Highway: g = sigmoid(ys @ Wt_hw^T + b_hw); v = g*ys + (1-g)*cur.
// Dual outputs: Outb (bf16, may be null) / OutF (fp32 final, may be null).
// Cur/Outb may alias (owner-thread read-before-write); Ys never aliases.
// EXACT R5 code (passing).
// ---------------------------------------------------------------------------
__launch_bounds__(256) __global__
void k_highway(const u16* __restrict__ Ys, const u16* Cur,
               const u16* __restrict__ Wt, const float* __restrict__ bias,
               u16* Outb, float* OutF) {
  const int m0 = blockIdx.x * 128;
  const int n0 = blockIdx.y * 128;

  __shared__ u16 lA[128 * 40];
  __shared__ u16 lB[128 * 40];

  const int tid = threadIdx.x;
  const int wave = tid >> 6, lane = tid & 63, quad = lane >> 4, l15 = lane & 15;
  const int wy = wave >> 1, wx = wave & 1;
  const int r = tid >> 2, kc = tid & 3;

  f32x4 acc[4][4];
#pragma unroll
  for (int i = 0; i < 4; ++i)
#pragma unroll
    for (int j = 0; j < 4; ++j)
#pragma unroll
      for (int k = 0; k < 4; ++k) acc[i][j][k] = 0.f;

  for (int kk = 0; kk < 16; ++kk) {
    const u16* Ap = Ys + (size_t)(m0 + r) * 512 + kk * 32 + kc * 8;
    uint4 a0 = *(const uint4*)Ap;
    uint4 a1 = *(const uint4*)(Ap + (size_t)64 * 512);
    const u16* Bp = Wt + (size_t)(n0 + r) * 512 + kk * 32 + kc * 8;
    uint4 b0 = *(const uint4*)Bp;
    uint4 b1 = *(const uint4*)(Bp + (size_t)64 * 512);
    __syncthreads();
    *(uint4*)&lA[r * 40 + kc * 8] = a0;
    *(uint4*)&lA[(r + 64) * 40 + kc * 8] = a1;
    *(uint4*)&lB[r * 40 + kc * 8] = b0;
    *(uint4*)&lB[(r + 64) * 40 + kc * 8] = b1;
    __syncthreads();
    short8 af[4], bf[4];
#pragma unroll
    for (int mt = 0; mt < 4; ++mt)
      af[mt] = *(const short8*)&lA[(wy * 64 + mt * 16 + l15) * 40 + quad * 8];
#pragma unroll
    for (int nt = 0; nt < 4; ++nt)
      bf[nt] = *(const short8*)&lB[(wx * 64 + nt * 16 + l15) * 40 + quad * 8];
#pragma unroll
    for (int mt = 0; mt < 4; ++mt)
#pragma unroll
      for (int nt = 0; nt < 4; ++nt) acc[mt][nt] = MFMA16(af[mt], bf[nt], acc[mt][nt]);
  }

#pragma unroll
  for (int nt = 0; nt < 4; ++nt) {
    const int col = n0 + wx * 64 + nt * 16 + l15;
    const float bv = bias[col];
#pragma unroll
    for (int mt = 0; mt < 4; ++mt) {
      const int mbase = m0 + wy * 64 + mt * 16 + quad * 4;
#pragma unroll
      for (int rr = 0; rr < 4; ++rr) {
        const size_t idx = (size_t)(mbase + rr) * 512 + col;
        const float g = sigm(acc[mt][nt][rr] + bv);
        const float v = g * b2f(Ys[idx]) + (1.f - g) * b2f(Cur[idx]);
        if (Outb) Outb[idx] = f2b(v);
        if (OutF) OutF[idx] = v;
      }
    }
  }
}

// ---------------------------------------------------------------------------
// Scan: 4 independent blocks (dir = bx>>1, batch-half bh = bx&1), block=512.
// R5 dataflow (row-major fp16 Z, scattered u16 reads) + three latency fixes:
// waves_per_eu(2,2) [256-VGPR budget for the 192-VGPR wB], one-step-ahead Z
// prefetch into u16 regs, double-buffered h_lds (one barrier/step).
// ---------------------------------------------------------------------------
__global__ __attribute__((amdgpu_flat_work_group_size(512, 512), amdgpu_waves_per_eu(2, 2)))
void k_scan(const u16* __restrict__ ZF, const u16* __restrict__ ZB,
            const u16* __restrict__ WtF, const u16* __restrict__ WtB,
            int wt_pitch, int koff,
            const float* __restrict__ h0, const float* __restrict__ c0,
            u16* __restrict__ ys,            // bf16 [32768][512]; fwd 0-255, bwd 256-511
            float* __restrict__ hn, float* __restrict__ cn) {  // fp32, + dir*8192
  const int tid = threadIdx.x;
  const int wid = tid >> 6, lane = tid & 63, quad = lane >> 4, l15 = lane & 15;
  const int dir = blockIdx.x >> 1, bh = blockIdx.x & 1;
  const u16* Z = dir ? ZB : ZF;
  const u16* Wt = dir ? WtB : WtF;

  __shared__ u16 h_lds[2][16 * 264];  // double-buffered [b][k], pitch 264

  // persistent W_h B-fragments: col n = g*256 + wid*32 + nt*16 + l15
  short8 wB[3][2][8];
#pragma unroll
  for (int g = 0; g < 3; ++g)
#pragma unroll
    for (int nt = 0; nt < 2; ++nt) {
      const u16* wrow =
          Wt + (size_t)(g * 256 + wid * 32 + nt * 16 + l15) * wt_pitch + koff + quad * 8;
#pragma unroll
      for (int kk = 0; kk < 8; ++kk) wB[g][nt][kk] = *(const short8*)(wrow + kk * 32);
    }

  // init h_lds[0] (broadcast h0; zero pad) and c regs
  for (int i = tid; i < 16 * 264; i += 512) {
    int k = i % 264;
    h_lds[0][i] = (k < 256) ? f2b(h0[k]) : (u16)0;
  }
  float cst[2][4];
#pragma unroll
  for (int nt = 0; nt < 2; ++nt) {
    const float cv = c0[wid * 32 + nt * 16 + l15];
#pragma unroll
    for (int rr = 0; rr < 4; ++rr) cst[nt][rr] = cv;
  }
  __syncthreads();

  // per-lane Z base: row (tt*32 + bh*16 + quad*4), col (wid*32 + l15);
  // per-(g,nt,rr) deltas are compile-time immediates.
  const size_t zlane = ((size_t)bh * 16 + quad * 4) * 768 + wid * 32 + l15;

  // preload step 0
  u16 znx[3][2][4];
  {
    const int tt0 = dir ? 1023 : 0;
    const u16* zp = Z + (size_t)tt0 * 32 * 768 + zlane;
#pragma unroll
    for (int g = 0; g < 3; ++g)
#pragma unroll
      for (int nt = 0; nt < 2; ++nt)
#pragma unroll
        for (int rr = 0; rr < 4; ++rr)
          znx[g][nt][rr] = zp[(size_t)rr * 768 + g * 256 + nt * 16];
  }

  int par = 0;
  for (int t = 0; t < 1024; ++t) {
    const int tt = dir ? (1023 - t) : t;

    // acc init from znx (loaded last iteration; vmcnt wait lands here)
    f32x4 acc[3][2];
#pragma unroll
    for (int g = 0; g < 3; ++g)
#pragma unroll
      for (int nt = 0; nt < 2; ++nt)
#pragma unroll
        for (int rr = 0; rr < 4; ++rr)
          acc[g][nt][rr] = h2f(znx[g][nt][rr]);

    // issue prefetch for step t+1 (WAR on znx: issued after the reads above)
    if (t < 1023) {
      const int ttn = dir ? (1022 - t) : (t + 1);
      const u16* zp = Z + (size_t)ttn * 32 * 768 + zlane;
#pragma unroll
      for (int g = 0; g < 3; ++g)
#pragma unroll
        for (int nt = 0; nt < 2; ++nt)
#pragma unroll
          for (int rr = 0; rr < 4; ++rr)
            znx[g][nt][rr] = zp[(size_t)rr * 768 + g * 256 + nt * 16];
    }

    // recurrent GEMM: h(t)[16x256] @ W_h
#pragma unroll
    for (int kk = 0; kk < 8; ++kk) {
      short8 a = *(const short8*)&h_lds[par][l15 * 264 + kk * 32 + quad * 8];
#pragma unroll
      for (int g = 0; g < 3; ++g)
#pragma unroll
        for (int nt = 0; nt < 2; ++nt) acc[g][nt] = MFMA16(a, wB[g][nt][kk], acc[g][nt]);
    }

    // gates: i=sig, j=tanh, o=sig; c=(1-i)c + i*j; h=tanh(c)*o
    u16 hv[2][4];
    float hf[2][4];
#pragma unroll
    for (int nt = 0; nt < 2; ++nt)
#pragma unroll
      for (int rr = 0; rr < 4; ++rr) {
        const float iv = sigm(acc[0][nt][rr]);
        const float jv = tanh_f(acc[1][nt][rr]);
        const float ov = sigm(acc[2][nt][rr]);
        const float c = (1.f - iv) * cst[nt][rr] + iv * jv;
        cst[nt][rr] = c;
        const float h = tanh_f(c) * ov;
        hf[nt][rr] = h;
        hv[nt][rr] = f2b(h);
      }

    // emit ys[tt]
#pragma unroll
    for (int nt = 0; nt < 2; ++nt) {
      const int col = wid * 32 + nt * 16 + l15;
#pragma unroll
      for (int rr = 0; rr < 4; ++rr) {
        const int b = bh * 16 + quad * 4 + rr;
        ys[((size_t)tt * 32 + b) * 512 + dir * 256 + col] = hv[nt][rr];
      }
    }
    if (t == 1023) {
#pragma unroll
      for (int nt = 0; nt < 2; ++nt) {
        const int col = wid * 32 + nt * 16 + l15;
#pragma unroll
        for (int rr = 0; rr < 4; ++rr) {
          const int b = bh * 16 + quad * 4 + rr;
          hn[dir * 8192 + b * 256 + col] = hf[nt][rr];
          cn[dir * 8192 + b * 256 + col] = cst[nt][rr];
        }
      }
      break;
    }

    // write h(t+1) into the OTHER buffer; one barrier
#pragma unroll
    for (int nt = 0; nt < 2; ++nt) {
      const int col = wid * 32 + nt * 16 + l15;
#pragma unroll
      for (int rr = 0; rr < 4; ++rr)
        h_lds[par ^ 1][(quad * 4 + rr) * 264 + col] = hv[nt][rr];
    }
    __syncthreads();
    par ^= 1;
  }
}

// ---------------------------------------------------------------------------
extern "C" void kernel_launch(void* const* d_in, const int* in_sizes, int n_in,
                              void* d_out, int out_size, void* d_ws, size_t ws_size,
                              hipStream_t stream) {
  const float* x = (const float*)d_in[0];
  const float* h0 = (const float*)d_in[1];
  const float* c0 = (const float*)d_in[2];
  const float* Wf0 = (const float*)d_in[3];
  const float* bf0 = (const float*)d_in[4];
  const float* Wb0 = (const float*)d_in[5];
  const float* bb0 = (const float*)d_in[6];
  const float* Wf1 = (const float*)d_in[7];
  const float* bf1 = (const float*)d_in[8];
  const float* Wb1 = (const float*)d_in[9];
  const float* bb1 = (const float*)d_in[10];
  const float* Wf2 = (const float*)d_in[11];
  const float* bf2 = (const float*)d_in[12];
  const float* Wb2 = (const float*)d_in[13];
  const float* bb2 = (const float*)d_in[14];
  const float* Whw = (const float*)d_in[15];
  const float* bhw = (const float*)d_in[16];
  float* out = (float*)d_out;  // fp32 (reference output dtype)

  // ws layout (~182.5 MiB)
  u16* Zf = (u16*)d_ws;                // 25165824 u16 (fp16 row-major, 48 MiB)
  u16* Zb = Zf + 25165824;             // 48 MiB
  u16* bufA = Zb + 25165824;           // 16777216 bf16 (32 MiB)
  u16* bufB = bufA + 16777216;         // 16777216 bf16 (32 MiB)
  u16* xb = bufB + 16777216;           // 8388608 bf16 (16 MiB)
  u16* Wt = xb + 8388608;              // 3407872 bf16 (6.5 MiB)

  u16* Wt0f = Wt;
  u16* Wt0b = Wt0f + 393216;
  u16* Wt1f = Wt0b + 393216;
  u16* Wt1b = Wt1f + 589824;
  u16* Wt2f = Wt1b + 589824;
  u16* Wt2b = Wt2f + 589824;
  u16* Wthw = Wt2b + 589824;

  float* hnb = out + 16777216;  // h_n [6][32][256] fp32
  float* cnb = hnb + 49152;     // c_n [6][32][256] fp32

  k_convert<<<8192, 256, 0, stream>>>(x, xb, 2097152);
  k_transpose<<<dim3(2304, 7), 256, 0, stream>>>(Wf0, Wb0, Wf1, Wb1, Wf2, Wb2, Whw, Wt);

  // layer 0 (Kin=256, Wt pitch 512): ys -> bufA (no highway)
  k_pregemm<<<dim3(256, 6, 2), 256, 0, stream>>>(xb, 256, Wt0f, Wt0b, 512, bf0, bb0, Zf, Zb);
  k_scan<<<dim3(4), 512, 0, stream>>>(Zf, Zb, Wt0f, Wt0b, 512, 256, h0, c0, bufA,
                                      hnb + 0 * 8192, cnb + 0 * 8192);

  // layer 1 (Kin=512, pitch 768): ys -> bufB; highway(Ys=bufB, Cur=bufA) -> bufA (bf16)
  k_pregemm<<<dim3(256, 6, 2), 256, 0, stream>>>(bufA, 512, Wt1f, Wt1b, 768, bf1, bb1, Zf, Zb);
  k_scan<<<dim3(4), 512, 0, stream>>>(Zf, Zb, Wt1f, Wt1b, 768, 512, h0, c0, bufB,
                                      hnb + 2 * 8192, cnb + 2 * 8192);
  k_highway<<<dim3(256, 4), 256, 0, stream>>>(bufB, bufA, Wthw, bhw, bufA, (float*)nullptr);

  // layer 2: ys -> bufB; highway(Ys=bufB, Cur=bufA) -> out (fp32, final)
  k_pregemm<<<dim3(256, 6, 2), 256, 0, stream>>>(bufA, 512, Wt2f, Wt2b, 768, bf2, bb2, Zf, Zb);
  k_scan<<<dim3(4), 512, 0, stream>>>(Zf, Zb, Wt2f, Wt2b, 768, 512, h0, c0, bufB,
                                      hnb + 4 * 8192, cnb + 4 * 8192);
  k_highway<<<dim3(256, 4), 256, 0, stream>>>(bufB, bufA, Wthw, bhw, (u16*)nullptr, out);
}

// Round 8
// 11305.965 us; speedup vs baseline: 1.3137x; 1.3137x over previous
//
#include <hip/hip_runtime.h>
#include <stdint.h>

// BiLSTM (3-layer, bidirectional, 3-gate custom cell, highway) for MI355X.
//
// R8: force W_h register residency in the scan.
// Evidence R5/R7: VGPR_Count=128 both rounds, scan ~3.7-4.7 us/step, HBM
// ~18 GB/s, VALUBusy(active CUs)~55%. Model: Wt is const __restrict__, so the
// compiler REMATERIALIZES the 192-VGPR wB fragment set from L2 every step
// (8 waves x 48 KB = 384 KB/CU/step ~= 3000 cyc -- matches). Fix: make remat
// illegal -- Wt passed non-const/non-restrict + a never-taken store inside
// the t-loop whose condition depends on t (can't be unswitched or proven
// false: (t ^ wt_pitch) == 0xdeadbeef). With waves_per_eu(2,2) the allocator
// then holds wB in the 256-reg budget. R7's Z-prefetch (regression) dropped;
// R7's double-buffered h_lds (passed) kept.
// Dataflow identical to the R5/R7 PASS (absmax 4.7e-3). Outputs fp32.

typedef unsigned short u16;
typedef unsigned int u32;
typedef unsigned long long u64;
typedef __attribute__((ext_vector_type(8))) short short8;   // 8 bf16
typedef __attribute__((ext_vector_type(4))) float f32x4;

#define MFMA16(a, b, c) __builtin_amdgcn_mfma_f32_16x16x32_bf16((a), (b), (c), 0, 0, 0)

__device__ __forceinline__ float b2f(u16 u) {
  u32 v = ((u32)u) << 16;
  return __builtin_bit_cast(float, v);
}
__device__ __forceinline__ u16 f2b(float f) {  // round-to-nearest-even
  u32 u = __builtin_bit_cast(u32, f);
  u32 r = u + 0x7FFFu + ((u >> 16) & 1u);
  return (u16)(r >> 16);
}
__device__ __forceinline__ u16 f2h(float f) {  // fp32 -> fp16 bits
  return __builtin_bit_cast(u16, (_Float16)f);
}
__device__ __forceinline__ float h2f(u16 u) {  // fp16 bits -> fp32
  return (float)__builtin_bit_cast(_Float16, u);
}
// Overflow-proof activations: exp args always <= 0 -> no inf/NaN possible.
__device__ __forceinline__ float sigm(float x) {
  const float q = __expf(-fabsf(x));
  const float r = 1.f / (1.f + q);
  return x >= 0.f ? r : 1.f - r;
}
__device__ __forceinline__ float tanh_f(float x) {
  const float q = __expf(-2.f * fabsf(x));
  const float t = (1.f - q) / (1.f + q);
  return x >= 0.f ? t : -t;
}

// ---------------------------------------------------------------------------
// Convert x (fp32) -> bf16, vectorized float4.
// ---------------------------------------------------------------------------
__global__ void k_convert(const float* __restrict__ src, u16* __restrict__ dst, int n4) {
  int i = blockIdx.x * 256 + threadIdx.x;
  if (i < n4) {
    float4 v = ((const float4*)src)[i];
    ushort4 o;
    o.x = f2b(v.x); o.y = f2b(v.y); o.z = f2b(v.z); o.w = f2b(v.w);
    ((ushort4*)dst)[i] = o;
  }
}

// ---------------------------------------------------------------------------
// Transpose + convert all weight matrices (fp32 W[R][C] -> bf16 Wt[C][R]).
// ---------------------------------------------------------------------------
__global__ void k_transpose(const float* __restrict__ w0, const float* __restrict__ w1,
                            const float* __restrict__ w2, const float* __restrict__ w3,
                            const float* __restrict__ w4, const float* __restrict__ w5,
                            const float* __restrict__ w6, u16* __restrict__ wt) {
  int z = blockIdx.y;
  const float* src;
  int R, C;
  size_t off;
  switch (z) {
    case 0: src = w0; R = 512; C = 768; off = 0u; break;
    case 1: src = w1; R = 512; C = 768; off = 393216u; break;
    case 2: src = w2; R = 768; C = 768; off = 786432u; break;
    case 3: src = w3; R = 768; C = 768; off = 1376256u; break;
    case 4: src = w4; R = 768; C = 768; off = 1966080u; break;
    case 5: src = w5; R = 768; C = 768; off = 2555904u; break;
    default: src = w6; R = 512; C = 512; off = 3145728u; break;
  }
  size_t total = (size_t)R * C;
  size_t e = (size_t)blockIdx.x * 256 + threadIdx.x;
  if (e < total) {
    int cc = (int)(e / (size_t)R);
    int rr = (int)(e - (size_t)cc * R);
    wt[off + e] = f2b(src[(size_t)rr * C + cc]);
  }
}

// ---------------------------------------------------------------------------
// Pre-GEMM: Z[m][n] = fp16( sum_k A[m][k]*Wt[n][k] + bias[n] )  (row-major)
// A bf16 [32768][Ka]; grid=(256, 6, 2[dir]); block=256; 128x128 tile.
// EXACT R5 code (passing).
// ---------------------------------------------------------------------------
__launch_bounds__(256) __global__
void k_pregemm(const u16* __restrict__ A, int Ka,
               const u16* __restrict__ WtF, const u16* __restrict__ WtB, int Kb,
               const float* __restrict__ biasF, const float* __restrict__ biasB,
               u16* __restrict__ ZF, u16* __restrict__ ZB) {
  const int dir = blockIdx.z;
  const u16* Bt = dir ? WtB : WtF;
  const float* bias = dir ? biasB : biasF;
  u16* Z = dir ? ZB : ZF;
  const int m0 = blockIdx.x * 128;
  const int n0 = blockIdx.y * 128;

  __shared__ u16 lA[128 * 40];
  __shared__ u16 lB[128 * 40];

  const int tid = threadIdx.x;
  const int wave = tid >> 6, lane = tid & 63, quad = lane >> 4, l15 = lane & 15;
  const int wy = wave >> 1, wx = wave & 1;
  const int r = tid >> 2, kc = tid & 3;

  f32x4 acc[4][4];
#pragma unroll
  for (int i = 0; i < 4; ++i)
#pragma unroll
    for (int j = 0; j < 4; ++j)
#pragma unroll
      for (int k = 0; k < 4; ++k) acc[i][j][k] = 0.f;

  const int nk = Ka >> 5;
  for (int kk = 0; kk < nk; ++kk) {
    const u16* Ap = A + (size_t)(m0 + r) * Ka + kk * 32 + kc * 8;
    uint4 a0 = *(const uint4*)Ap;
    uint4 a1 = *(const uint4*)(Ap + (size_t)64 * Ka);
    const u16* Bp = Bt + (size_t)(n0 + r) * Kb + kk * 32 + kc * 8;
    uint4 b0 = *(const uint4*)Bp;
    uint4 b1 = *(const uint4*)(Bp + (size_t)64 * Kb);
    __syncthreads();
    *(uint4*)&lA[r * 40 + kc * 8] = a0;
    *(uint4*)&lA[(r + 64) * 40 + kc * 8] = a1;
    *(uint4*)&lB[r * 40 + kc * 8] = b0;
    *(uint4*)&lB[(r + 64) * 40 + kc * 8] = b1;
    __syncthreads();
    short8 af[4], bf[4];
#pragma unroll
    for (int mt = 0; mt < 4; ++mt)
      af[mt] = *(const short8*)&lA[(wy * 64 + mt * 16 + l15) * 40 + quad * 8];
#pragma unroll
    for (int nt = 0; nt < 4; ++nt)
      bf[nt] = *(const short8*)&lB[(wx * 64 + nt * 16 + l15) * 40 + quad * 8];
#pragma unroll
    for (int mt = 0; mt < 4; ++mt)
#pragma unroll
      for (int nt = 0; nt < 4; ++nt) acc[mt][nt] = MFMA16(af[mt], bf[nt], acc[mt][nt]);
  }

#pragma unroll
  for (int nt = 0; nt < 4; ++nt) {
    const int col = n0 + wx * 64 + nt * 16 + l15;
    const float bv = bias[col];
#pragma unroll
    for (int mt = 0; mt < 4; ++mt) {
      const int mbase = m0 + wy * 64 + mt * 16 + quad * 4;
#pragma unroll
      for (int rr = 0; rr < 4; ++rr)
        Z[(size_t)(mbase + rr) * 768 + col] = f2h(acc[mt][nt][rr] + bv);
    }
  }
}

// ---------------------------------------------------------------------------
// Highway: g = sigmoid(ys @ Wt_hw^T + b_hw); v = g*ys + (1-g)*cur.
// Dual outputs: Outb (bf16, may be null) / OutF (fp32 final, may be null).
// Cur/Outb may alias (owner-thread read-before-write); Ys never aliases.
// EXACT R5 code (passing).
// ---------------------------------------------------------------------------
__launch_bounds__(256) __global__
void k_highway(const u16* __restrict__ Ys, const u16* Cur,
               const u16* __restrict__ Wt, const float* __restrict__ bias,
               u16* Outb, float* OutF) {
  const int m0 = blockIdx.x * 128;
  const int n0 = blockIdx.y * 128;

  __shared__ u16 lA[128 * 40];
  __shared__ u16 lB[128 * 40];

  const int tid = threadIdx.x;
  const int wave = tid >> 6, lane = tid & 63, quad = lane >> 4, l15 = lane & 15;
  const int wy = wave >> 1, wx = wave & 1;
  const int r = tid >> 2, kc = tid & 3;

  f32x4 acc[4][4];
#pragma unroll
  for (int i = 0; i < 4; ++i)
#pragma unroll
    for (int j = 0; j < 4; ++j)
#pragma unroll
      for (int k = 0; k < 4; ++k) acc[i][j][k] = 0.f;

  for (int kk = 0; kk < 16; ++kk) {
    const u16* Ap = Ys + (size_t)(m0 + r) * 512 + kk * 32 + kc * 8;
    uint4 a0 = *(const uint4*)Ap;
    uint4 a1 = *(const uint4*)(Ap + (size_t)64 * 512);
    const u16* Bp = Wt + (size_t)(n0 + r) * 512 + kk * 32 + kc * 8;
    uint4 b0 = *(const uint4*)Bp;
    uint4 b1 = *(const uint4*)(Bp + (size_t)64 * 512);
    __syncthreads();
    *(uint4*)&lA[r * 40 + kc * 8] = a0;
    *(uint4*)&lA[(r + 64) * 40 + kc * 8] = a1;
    *(uint4*)&lB[r * 40 + kc * 8] = b0;
    *(uint4*)&lB[(r + 64) * 40 + kc * 8] = b1;
    __syncthreads();
    short8 af[4], bf[4];
#pragma unroll
    for (int mt = 0; mt < 4; ++mt)
      af[mt] = *(const short8*)&lA[(wy * 64 + mt * 16 + l15) * 40 + quad * 8];
#pragma unroll
    for (int nt = 0; nt < 4; ++nt)
      bf[nt] = *(const short8*)&lB[(wx * 64 + nt * 16 + l15) * 40 + quad * 8];
#pragma unroll
    for (int mt = 0; mt < 4; ++mt)
#pragma unroll
      for (int nt = 0; nt < 4; ++nt) acc[mt][nt] = MFMA16(af[mt], bf[nt], acc[mt][nt]);
  }

#pragma unroll
  for (int nt = 0; nt < 4; ++nt) {
    const int col = n0 + wx * 64 + nt * 16 + l15;
    const float bv = bias[col];
#pragma unroll
    for (int mt = 0; mt < 4; ++mt) {
      const int mbase = m0 + wy * 64 + mt * 16 + quad * 4;
#pragma unroll
      for (int rr = 0; rr < 4; ++rr) {
        const size_t idx = (size_t)(mbase + rr) * 512 + col;
        const float g = sigm(acc[mt][nt][rr] + bv);
        const float v = g * b2f(Ys[idx]) + (1.f - g) * b2f(Cur[idx]);
        if (Outb) Outb[idx] = f2b(v);
        if (OutF) OutF[idx] = v;
      }
    }
  }
}

// ---------------------------------------------------------------------------
// Scan: 4 independent blocks (dir = bx>>1, batch-half bh = bx&1), block=512.
// wB (192 VGPRs of W_h fragments) must stay resident: Wt is non-const/non-
// restrict and a never-taken, t-dependent store inside the loop forbids
// rematerialization of the weight loads. waves_per_eu(2,2) grants the
// 256-VGPR budget. Z loads inline (R5 style). h_lds double-buffered.
// ---------------------------------------------------------------------------
__global__ __attribute__((amdgpu_flat_work_group_size(512, 512), amdgpu_waves_per_eu(2, 2)))
void k_scan(const u16* __restrict__ ZF, const u16* __restrict__ ZB,
            u16* WtF, u16* WtB,            // NOT const/restrict: remat-breaker
            int wt_pitch, int koff,
            const float* __restrict__ h0, const float* __restrict__ c0,
            u16* __restrict__ ys,            // bf16 [32768][512]; fwd 0-255, bwd 256-511
            float* __restrict__ hn, float* __restrict__ cn) {  // fp32, + dir*8192
  const int tid = threadIdx.x;
  const int wid = tid >> 6, lane = tid & 63, quad = lane >> 4, l15 = lane & 15;
  const int dir = blockIdx.x >> 1, bh = blockIdx.x & 1;
  const u16* Z = dir ? ZB : ZF;
  u16* Wt = dir ? WtB : WtF;

  __shared__ u16 h_lds[2][16 * 264];  // double-buffered [b][k], pitch 264

  // persistent W_h B-fragments: col n = g*256 + wid*32 + nt*16 + l15
  short8 wB[3][2][8];
#pragma unroll
  for (int g = 0; g < 3; ++g)
#pragma unroll
    for (int nt = 0; nt < 2; ++nt) {
      const u16* wrow =
          Wt + (size_t)(g * 256 + wid * 32 + nt * 16 + l15) * wt_pitch + koff + quad * 8;
#pragma unroll
      for (int kk = 0; kk < 8; ++kk) wB[g][nt][kk] = *(const short8*)(wrow + kk * 32);
    }

  // init h_lds[0] (broadcast h0; zero pad) and c regs
  for (int i = tid; i < 16 * 264; i += 512) {
    int k = i % 264;
    h_lds[0][i] = (k < 256) ? f2b(h0[k]) : (u16)0;
  }
  float cst[2][4];
#pragma unroll
  for (int nt = 0; nt < 2; ++nt) {
    const float cv = c0[wid * 32 + nt * 16 + l15];
#pragma unroll
    for (int rr = 0; rr < 4; ++rr) cst[nt][rr] = cv;
  }
  __syncthreads();

  // per-lane Z base: row (tt*32 + bh*16 + quad*4), col (wid*32 + l15)
  const size_t zlane = ((size_t)bh * 16 + quad * 4) * 768 + wid * 32 + l15;

  int par = 0;
  for (int t = 0; t < 1024; ++t) {
    const int tt = dir ? (1023 - t) : t;

    // Remat-breaker: never true (t < 1024, xor can't reach 0xdeadbeef unless
    // wt_pitch were adversarial -- it's 512/768), but the compiler can't
    // prove it, can't unswitch it (t-dependent), so Wt loads can't be
    // rematerialized across iterations -> wB must stay in registers.
    if (((u32)t ^ (u32)wt_pitch) == 0xdeadbeefu) Wt[t] = (u16)t;

    // acc init from fp16 Z (bias included) -- inline loads, R5 style
    const u16* zp = Z + (size_t)tt * 32 * 768 + zlane;
    f32x4 acc[3][2];
#pragma unroll
    for (int g = 0; g < 3; ++g)
#pragma unroll
      for (int nt = 0; nt < 2; ++nt)
#pragma unroll
        for (int rr = 0; rr < 4; ++rr)
          acc[g][nt][rr] = h2f(zp[(size_t)rr * 768 + g * 256 + nt * 16]);

    // recurrent GEMM: h(t)[16x256] @ W_h
#pragma unroll
    for (int kk = 0; kk < 8; ++kk) {
      short8 a = *(const short8*)&h_lds[par][l15 * 264 + kk * 32 + quad * 8];
#pragma unroll
      for (int g = 0; g < 3; ++g)
#pragma unroll
        for (int nt = 0; nt < 2; ++nt) acc[g][nt] = MFMA16(a, wB[g][nt][kk], acc[g][nt]);
    }

    // gates: i=sig, j=tanh, o=sig; c=(1-i)c + i*j; h=tanh(c)*o
    u16 hv[2][4];
    float hf[2][4];
#pragma unroll
    for (int nt = 0; nt < 2; ++nt)
#pragma unroll
      for (int rr = 0; rr < 4; ++rr) {
        const float iv = sigm(acc[0][nt][rr]);
        const float jv = tanh_f(acc[1][nt][rr]);
        const float ov = sigm(acc[2][nt][rr]);
        const float c = (1.f - iv) * cst[nt][rr] + iv * jv;
        cst[nt][rr] = c;
        const float h = tanh_f(c) * ov;
        hf[nt][rr] = h;
        hv[nt][rr] = f2b(h);
      }

    // emit ys[tt]
#pragma unroll
    for (int nt = 0; nt < 2; ++nt) {
      const int col = wid * 32 + nt * 16 + l15;
#pragma unroll
      for (int rr = 0; rr < 4; ++rr) {
        const int b = bh * 16 + quad * 4 + rr;
        ys[((size_t)tt * 32 + b) * 512 + dir * 256 + col] = hv[nt][rr];
      }
    }
    if (t == 1023) {
#pragma unroll
      for (int nt = 0; nt < 2; ++nt) {
        const int col = wid * 32 + nt * 16 + l15;
#pragma unroll
        for (int rr = 0; rr < 4; ++rr) {
          const int b = bh * 16 + quad * 4 + rr;
          hn[dir * 8192 + b * 256 + col] = hf[nt][rr];
          cn[dir * 8192 + b * 256 + col] = cst[nt][rr];
        }
      }
      break;
    }

    // write h(t+1) into the OTHER buffer; one barrier
#pragma unroll
    for (int nt = 0; nt < 2; ++nt) {
      const int col = wid * 32 + nt * 16 + l15;
#pragma unroll
      for (int rr = 0; rr < 4; ++rr)
        h_lds[par ^ 1][(quad * 4 + rr) * 264 + col] = hv[nt][rr];
    }
    __syncthreads();
    par ^= 1;
  }
}

// ---------------------------------------------------------------------------
extern "C" void kernel_launch(void* const* d_in, const int* in_sizes, int n_in,
                              void* d_out, int out_size, void* d_ws, size_t ws_size,
                              hipStream_t stream) {
  const float* x = (const float*)d_in[0];
  const float* h0 = (const float*)d_in[1];
  const float* c0 = (const float*)d_in[2];
  const float* Wf0 = (const float*)d_in[3];
  const float* bf0 = (const float*)d_in[4];
  const float* Wb0 = (const float*)d_in[5];
  const float* bb0 = (const float*)d_in[6];
  const float* Wf1 = (const float*)d_in[7];
  const float* bf1 = (const float*)d_in[8];
  const float* Wb1 = (const float*)d_in[9];
  const float* bb1 = (const float*)d_in[10];
  const float* Wf2 = (const float*)d_in[11];
  const float* bf2 = (const float*)d_in[12];
  const float* Wb2 = (const float*)d_in[13];
  const float* bb2 = (const float*)d_in[14];
  const float* Whw = (const float*)d_in[15];
  const float* bhw = (const float*)d_in[16];
  float* out = (float*)d_out;  // fp32 (reference output dtype)

  // ws layout (~182.5 MiB)
  u16* Zf = (u16*)d_ws;                // 25165824 u16 (fp16 row-major, 48 MiB)
  u16* Zb = Zf + 25165824;             // 48 MiB
  u16* bufA = Zb + 25165824;           // 16777216 bf16 (32 MiB)
  u16* bufB = bufA + 16777216;         // 16777216 bf16 (32 MiB)
  u16* xb = bufB + 16777216;           // 8388608 bf16 (16 MiB)
  u16* Wt = xb + 8388608;              // 3407872 bf16 (6.5 MiB)

  u16* Wt0f = Wt;
  u16* Wt0b = Wt0f + 393216;
  u16* Wt1f = Wt0b + 393216;
  u16* Wt1b = Wt1f + 589824;
  u16* Wt2f = Wt1b + 589824;
  u16* Wt2b = Wt2f + 589824;
  u16* Wthw = Wt2b + 589824;

  float* hnb = out + 16777216;  // h_n [6][32][256] fp32
  float* cnb = hnb + 49152;     // c_n [6][32][256] fp32

  k_convert<<<8192, 256, 0, stream>>>(x, xb, 2097152);
  k_transpose<<<dim3(2304, 7), 256, 0, stream>>>(Wf0, Wb0, Wf1, Wb1, Wf2, Wb2, Whw, Wt);

  // layer 0 (Kin=256, Wt pitch 512): ys -> bufA (no highway)
  k_pregemm<<<dim3(256, 6, 2), 256, 0, stream>>>(xb, 256, Wt0f, Wt0b, 512, bf0, bb0, Zf, Zb);
  k_scan<<<dim3(4), 512, 0, stream>>>(Zf, Zb, Wt0f, Wt0b, 512, 256, h0, c0, bufA,
                                      hnb + 0 * 8192, cnb + 0 * 8192);

  // layer 1 (Kin=512, pitch 768): ys -> bufB; highway(Ys=bufB, Cur=bufA) -> bufA (bf16)
  k_pregemm<<<dim3(256, 6, 2), 256, 0, stream>>>(bufA, 512, Wt1f, Wt1b, 768, bf1, bb1, Zf, Zb);
  k_scan<<<dim3(4), 512, 0, stream>>>(Zf, Zb, Wt1f, Wt1b, 768, 512, h0, c0, bufB,
                                      hnb + 2 * 8192, cnb + 2 * 8192);
  k_highway<<<dim3(256, 4), 256, 0, stream>>>(bufB, bufA, Wthw, bhw, bufA, (float*)nullptr);

  // layer 2: ys -> bufB; highway(Ys=bufB, Cur=bufA) -> out (fp32, final)
  k_pregemm<<<dim3(256, 6, 2), 256, 0, stream>>>(bufA, 512, Wt2f, Wt2b, 768, bf2, bb2, Zf, Zb);
  k_scan<<<dim3(4), 512, 0, stream>>>(Zf, Zb, Wt2f, Wt2b, 768, 512, h0, c0, bufB,
                                      hnb + 4 * 8192, cnb + 4 * 8192);
  k_highway<<<dim3(256, 4), 256, 0, stream>>>(bufB, bufA, Wthw, bhw, (u16*)nullptr, out);
}